// Round 10
// baseline (267.813 us; speedup 1.0000x reference)
//
#include <hip/hip_runtime.h>
#include <hip/hip_bf16.h>
#include <stdint.h>

#define Mdim 8192
#define KSTEPS 256        // 8192 / 32

typedef __attribute__((ext_vector_type(8))) short short8v;  // 8 bf16
typedef __attribute__((ext_vector_type(4))) short short4v;  // 4 bf16
typedef __attribute__((ext_vector_type(4))) float f32x4;
typedef __attribute__((ext_vector_type(2))) float f32x2;

// f32 -> bf16 RNE via standard cast (compiler emits v_cvt_pk_bf16_f32)
static __device__ __forceinline__ short bf16c(float f) {
  __hip_bfloat16 h = __float2bfloat16(f);
  union { __hip_bfloat16 h; short s; } c; c.h = h;
  return c.s;
}

// Repack x (f32 [8192][32]) into MFMA B-fragment layout:
// Bp[((ks*2 + h)*64 + lane)*8 + j] = bf16( B[ks*32 + (lane>>4)*8 + j][h*16 + (lane&15)] )
__global__ __launch_bounds__(256)
void repack_x(const float* __restrict__ x, short* __restrict__ Bp)
{
  int t = blockIdx.x * 256 + threadIdx.x;       // 32768 threads total
  int l = t & 63, h = (t >> 6) & 1, ks = t >> 7;
  int col = h * 16 + (l & 15);
  int kbase = ks * 32 + ((l >> 4) << 3);
  short8v v;
#pragma unroll
  for (int j = 0; j < 8; ++j) v[j] = bf16c(x[(size_t)(kbase + j) * 32 + col]);
  reinterpret_cast<short8v*>(Bp)[t] = v;
}

// ---- convert body (512 thr = 8 waves): f32 L-slab -> bf16 fragment-linear
// + MFMA partial of T1 = L @ x. job = tile*8 + slab. sh: >= 33024 B.
static __device__ __forceinline__ void convert_body(
    char* sh, const float* __restrict__ src, const short* __restrict__ Bx,
    short* __restrict__ dst, float* __restrict__ Pt1, int job)
{
  short* Lb = reinterpret_cast<short*>(sh);   // [16][1032] shorts (+8 pad/row)
  const int tile = job >> 3;
  const int slab = job & 7;
  const int t = threadIdx.x;
  const int lane = t & 63;
  const int wid  = t >> 6;

  // phase 1: 16 rows x 1024 f32 -> bf16 in LDS (coalesced, nontemporal)
#pragma unroll
  for (int it = 0; it < 8; ++it) {
    const int s = it * 512 + t;               // 0..4095 = row*256 + c
    const int r = s >> 8, c = s & 255;
    const f32x4* p = reinterpret_cast<const f32x4*>(
        src + ((size_t)tile * 16 + r) * Mdim + slab * 1024) + c;
    f32x4 a = __builtin_nontemporal_load(p);
    short4v v; v[0] = bf16c(a[0]); v[1] = bf16c(a[1]); v[2] = bf16c(a[2]); v[3] = bf16c(a[3]);
    *reinterpret_cast<short4v*>(&Lb[r * 1032 + c * 4]) = v;
  }
  __syncthreads();

  // phase 2: write 32 fragment-linear records + MFMA partial T1
  const short8v* bx8 = reinterpret_cast<const short8v*>(Bx);
  f32x4 acc0 = {0.f, 0.f, 0.f, 0.f};
  f32x4 acc1 = {0.f, 0.f, 0.f, 0.f};
#pragma unroll
  for (int it = 0; it < 4; ++it) {
    const int ksl = it * 8 + wid;
    short8v av = *reinterpret_cast<const short8v*>(
        &Lb[(lane & 15) * 1032 + ksl * 32 + ((lane >> 4) << 3)]);
    reinterpret_cast<short8v*>(dst)[(size_t)(tile * 256 + slab * 32 + ksl) * 64 + lane] = av;
    const int gks = slab * 32 + ksl;
    short8v b0 = bx8[(size_t)(gks << 1) * 64 + lane];
    short8v b1 = bx8[(size_t)((gks << 1) + 1) * 64 + lane];
    acc0 = __builtin_amdgcn_mfma_f32_16x16x32_bf16(av, b0, acc0, 0, 0, 0);
    acc1 = __builtin_amdgcn_mfma_f32_16x16x32_bf16(av, b1, acc1, 0, 0, 0);
  }

  // cross-wave reduce of 8 partials (reuse LDS after barrier)
  __syncthreads();
  float* Clf = reinterpret_cast<float*>(sh);  // [8][16][32] = 16 KB
  {
    // C/D layout: col = lane&15, row = (lane>>4)*4 + reg  (m89-verified)
    const int crow = (lane >> 4) << 2;
    const int ccol = lane & 15;
#pragma unroll
    for (int q = 0; q < 4; ++q) {
      Clf[((wid * 16) + crow + q) * 32 + ccol] = acc0[q];
      Clf[((wid * 16) + crow + q) * 32 + 16 + ccol] = acc1[q];
    }
  }
  __syncthreads();
  {
    const int row = t >> 5, col = t & 31;     // 512 elems, 1/thread
    float v = 0.f;
#pragma unroll
    for (int s = 0; s < 8; ++s) v += Clf[((s * 16) + row) * 32 + col];
    Pt1[(size_t)job * 512 + t] = v;
  }
}

// ---- gemm body (512 thr = 8 waves, k-split 8 x 1024; round-9 proven) ----
// Tout = 2*(A @ B) - Tprev; A bf16 fragment-linear; sh >= 18432 B.
template<int WRITEB>
static __device__ __forceinline__ void gemm_body(
    char* sh, const short* __restrict__ As, const short* __restrict__ Bps,
    const float* __restrict__ Tprev, float* __restrict__ Tout,
    short* __restrict__ BpOut, int bTile)
{
  const int lane = threadIdx.x & 63;
  const int wid  = threadIdx.x >> 6;        // wave 0..7 -> k-chunk of 32 steps
  const int r0 = bTile << 4;
  const int ksbase = wid * 32;

  const short8v* aF = reinterpret_cast<const short8v*>(As)
                      + ((size_t)bTile * 256 + ksbase) * 64 + lane;
  const short8v* bF = reinterpret_cast<const short8v*>(Bps)
                      + (size_t)ksbase * 128 + lane;

  f32x4 acc0 = {0.f, 0.f, 0.f, 0.f};        // cols 0..15
  f32x4 acc1 = {0.f, 0.f, 0.f, 0.f};        // cols 16..31

#pragma unroll 8
  for (int ks = 0; ks < 32; ++ks) {
    short8v av = aF[ks * 64];
    short8v b0 = bF[ks * 128];
    short8v b1 = bF[ks * 128 + 64];
    acc0 = __builtin_amdgcn_mfma_f32_16x16x32_bf16(av, b0, acc0, 0, 0, 0);
    acc1 = __builtin_amdgcn_mfma_f32_16x16x32_bf16(av, b1, acc1, 0, 0, 0);
  }

  float* Cl   = reinterpret_cast<float*>(sh);          // [8][16][32] = 16 KB
  float* Cred = reinterpret_cast<float*>(sh + 16384);  // [16][32]    = 2 KB
  {
    const int crow = (lane >> 4) << 2;
    const int ccol = lane & 15;
#pragma unroll
    for (int q = 0; q < 4; ++q) {
      Cl[((wid * 16) + crow + q) * 32 + ccol] = acc0[q];
      Cl[((wid * 16) + crow + q) * 32 + 16 + ccol] = acc1[q];
    }
  }
  __syncthreads();
  {
    const int t = threadIdx.x;
    const int row = t >> 5, col = t & 31;
    float v = 0.f;
#pragma unroll
    for (int s = 0; s < 8; ++s) v += Cl[((s * 16) + row) * 32 + col];
    v = 2.f * v - Tprev[(size_t)r0 * 32 + t];
    Tout[(size_t)r0 * 32 + t] = v;
    if constexpr (WRITEB) Cred[row * 32 + col] = v;
  }
  if constexpr (WRITEB) {
    __syncthreads();
    if (threadIdx.x < 64) {
      const int t = threadIdx.x;
      const int ksOut = r0 >> 5;
      const int sub = (r0 >> 4) & 1;
      const int h = t >> 5;
      const int lp = (t & 31) + sub * 32;
      const int col = h * 16 + (lp & 15);
      const int lrbase = (lp & 16) ? 8 : 0;
      short8v v;
#pragma unroll
      for (int j = 0; j < 8; ++j) v[j] = bf16c(Cred[(lrbase + j) * 32 + col]);
      reinterpret_cast<short8v*>(BpOut)[(ksOut << 1 | h) * 64 + lp] = v;
    }
  }
}

// standalone convert+T1 kernel
__global__ __launch_bounds__(512)
void convert_t1(const float* __restrict__ src, const short* __restrict__ Bx,
                short* __restrict__ dst, float* __restrict__ Pt1)
{
  __shared__ __align__(16) char sh[33024];
  convert_body(sh, src, Bx, dst, Pt1, blockIdx.x);
}

// standalone gemm stage kernel
template<int WRITEB>
__global__ __launch_bounds__(512)
void gemm_stage(const short* __restrict__ As, const short* __restrict__ Bps,
                const float* __restrict__ Tprev, float* __restrict__ Tout,
                short* __restrict__ BpOut)
{
  __shared__ __align__(16) char sh[18432];
  gemm_body<WRITEB>(sh, As, Bps, Tprev, Tout, BpOut, blockIdx.x);
}

// FUSED: blocks 0..511 -> S3 of chain l (reads Llb, L3-warm);
//        blocks 512..4607 -> convert_t1 of chain u (streams Lu, HBM-bound).
// Overlaps the HBM-streaming convert with the L3-read gemm. Safe L3-wise:
// after S3l completes, Llb is dead, so Lub's allocations can't hurt.
__global__ __launch_bounds__(512)
void fused_conv_s3(const float* __restrict__ srcU, const short* __restrict__ Bx,
                   short* __restrict__ dstU, float* __restrict__ Pt1u,
                   const short* __restrict__ AsL, const short* __restrict__ BpsL,
                   const float* __restrict__ TprevL, float* __restrict__ ToutL)
{
  __shared__ __align__(16) char sh[33024];
  if (blockIdx.x < 512) {
    gemm_body<0>(sh, AsL, BpsL, TprevL, ToutL, nullptr, blockIdx.x);
  } else {
    convert_body(sh, srcU, Bx, dstU, Pt1u, blockIdx.x - 512);
  }
}

// Sum the 8 slab-partials -> T1 (f32) + T1 B-fragments.
__global__ __launch_bounds__(256)
void reduce_t1(const float* __restrict__ Pt1, float* __restrict__ Tout,
               short* __restrict__ BpOut)
{
  __shared__ float Cred[16][32];
  const int tile = blockIdx.x;
  const int t = threadIdx.x;
  const int e = t * 2;
  float s0 = 0.f, s1 = 0.f;
#pragma unroll
  for (int s = 0; s < 8; ++s) {
    f32x2 v = *reinterpret_cast<const f32x2*>(Pt1 + (size_t)(tile * 8 + s) * 512 + e);
    s0 += v[0]; s1 += v[1];
  }
  f32x2 o; o[0] = s0; o[1] = s1;
  *reinterpret_cast<f32x2*>(Tout + (size_t)tile * 512 + e) = o;
  Cred[e >> 5][e & 31] = s0;
  Cred[e >> 5][(e & 31) + 1] = s1;
  __syncthreads();
  if (t < 64) {
    const int r0 = tile << 4;
    const int ksOut = r0 >> 5;
    const int sub = (r0 >> 4) & 1;
    const int h = t >> 5;
    const int lp = (t & 31) + sub * 32;
    const int col = h * 16 + (lp & 15);
    const int lrbase = (lp & 16) ? 8 : 0;
    short8v v;
#pragma unroll
    for (int j = 0; j < 8; ++j) v[j] = bf16c(Cred[lrbase + j][col]);
    reinterpret_cast<short8v*>(BpOut)[(ksOut << 1 | h) * 64 + lp] = v;
  }
}

// Fallback f32-A stage (only if workspace lacks room for the bf16 copies).
template<int HASPREV>
__global__ __launch_bounds__(512)
void gemm_f32_stage(const float* __restrict__ Af, const short8v* __restrict__ Bp,
                    const float* __restrict__ Tprev, float* __restrict__ Tout,
                    short* __restrict__ BpOut)
{
  const int lane = threadIdx.x & 63;
  const int wid  = threadIdx.x >> 6;
  const int r0 = blockIdx.x << 4;
  const int arow = r0 + (lane & 15);
  const int koff = (lane >> 4) << 3;
  const int ksbase = wid * 32;

  f32x4 acc0 = {0.f, 0.f, 0.f, 0.f};
  f32x4 acc1 = {0.f, 0.f, 0.f, 0.f};

  const float* ap = Af + (size_t)arow * Mdim + ksbase * 32 + koff;
#pragma unroll 8
  for (int ks = 0; ks < 32; ++ks) {
    const int g = ksbase + ks;
    f32x4 a0 = *reinterpret_cast<const f32x4*>(ap);
    f32x4 a1 = *reinterpret_cast<const f32x4*>(ap + 4);
    short8v av;
#pragma unroll
    for (int j = 0; j < 4; ++j) av[j] = bf16c(a0[j]);
#pragma unroll
    for (int j = 0; j < 4; ++j) av[4 + j] = bf16c(a1[j]);
    short8v b0 = Bp[(g << 1) * 64 + lane];
    short8v b1 = Bp[((g << 1) + 1) * 64 + lane];
    acc0 = __builtin_amdgcn_mfma_f32_16x16x32_bf16(av, b0, acc0, 0, 0, 0);
    acc1 = __builtin_amdgcn_mfma_f32_16x16x32_bf16(av, b1, acc1, 0, 0, 0);
    ap += 32;
  }

  __shared__ float Cl[8][16][32];
  __shared__ float Cred[16][32];
  {
    const int crow = (lane >> 4) << 2;
    const int ccol = lane & 15;
#pragma unroll
    for (int q = 0; q < 4; ++q) {
      Cl[wid][crow + q][ccol] = acc0[q];
      Cl[wid][crow + q][16 + ccol] = acc1[q];
    }
  }
  __syncthreads();
  {
    const int t = threadIdx.x;
    const int row = t >> 5, col = t & 31;
    float v = Cl[0][row][col] + Cl[1][row][col] + Cl[2][row][col] + Cl[3][row][col]
            + Cl[4][row][col] + Cl[5][row][col] + Cl[6][row][col] + Cl[7][row][col];
    if constexpr (HASPREV) {
      v = 2.f * v - Tprev[(size_t)r0 * 32 + t];
    }
    Tout[(size_t)r0 * 32 + t] = v;
    Cred[row][col] = v;
  }
  __syncthreads();
  if (threadIdx.x < 64) {
    const int t = threadIdx.x;
    const int ksOut = r0 >> 5;
    const int sub = (r0 >> 4) & 1;
    const int h = t >> 5;
    const int lp = (t & 31) + sub * 32;
    const int col = h * 16 + (lp & 15);
    const int lrbase = (lp & 16) ? 8 : 0;
    short8v v;
#pragma unroll
    for (int j = 0; j < 8; ++j) v[j] = bf16c(Cred[lrbase + j][col]);
    reinterpret_cast<short8v*>(BpOut)[(ksOut << 1 | h) * 64 + lp] = v;
  }
}

// y[n][o] = sum_k sum_i Xk[n][i] * W[i][o][k],  W: [32][32][7] f32
__global__ __launch_bounds__(256)
void combine(const float* __restrict__ x,
             const float* __restrict__ T1l, const float* __restrict__ T2l,
             const float* __restrict__ T3l, const float* __restrict__ T1u,
             const float* __restrict__ T2u, const float* __restrict__ T3u,
             const float* __restrict__ W, float* __restrict__ y)
{
  __shared__ float Wl[7168];
  for (int i = threadIdx.x; i < 7168; i += 256) Wl[i] = W[i];
  __syncthreads();
  int t = blockIdx.x * 256 + threadIdx.x;
  int n = t >> 5, o = t & 31;
  const float* Xs[7] = {x, T1l, T2l, T3l, T1u, T2u, T3u};
  float sum = 0.f;
#pragma unroll
  for (int k = 0; k < 7; ++k) {
    const f32x4* Xr = reinterpret_cast<const f32x4*>(Xs[k] + (size_t)n * 32);
#pragma unroll
    for (int i4 = 0; i4 < 8; ++i4) {
      f32x4 xv = Xr[i4];
#pragma unroll
      for (int j = 0; j < 4; ++j)
        sum += xv[j] * Wl[(i4 * 4 + j) * 224 + o * 7 + k];
    }
  }
  y[t] = sum;
}

extern "C" void kernel_launch(void* const* d_in, const int* in_sizes, int n_in,
                              void* d_out, int out_size, void* d_ws, size_t ws_size,
                              hipStream_t stream)
{
  const float* x  = (const float*)d_in[0];
  const float* Ll = (const float*)d_in[1];
  const float* Lu = (const float*)d_in[2];
  const float* W  = (const float*)d_in[3];
  float* y = (float*)d_out;

  char* ws = (char*)d_ws;
  size_t off = 0;
  auto alloc = [&](size_t bytes) -> void* {
    void* p = ws + off; off += (bytes + 255) & ~(size_t)255; return p;
  };
  short* Bx = (short*)alloc(512 * 1024);
  short* B1 = (short*)alloc(512 * 1024);
  short* B2 = (short*)alloc(512 * 1024);
  float* T1l = (float*)alloc(1u << 20);
  float* T2l = (float*)alloc(1u << 20);
  float* T3l = (float*)alloc(1u << 20);
  float* T1u = (float*)alloc(1u << 20);
  float* T2u = (float*)alloc(1u << 20);
  float* T3u = (float*)alloc(1u << 20);
  float* Pt1 = (float*)alloc((size_t)512 * 8 * 512 * 4);   // 8 MB partials

  const size_t lbytes = (size_t)Mdim * Mdim * sizeof(short);
  bool useBF = (ws_size >= off + 2 * lbytes);
  short* Llb = nullptr; short* Lub = nullptr;
  if (useBF) { Llb = (short*)alloc(lbytes); Lub = (short*)alloc(lbytes); }

  repack_x<<<128, 256, 0, stream>>>(x, Bx);

  if (useBF) {
    // chain l
    convert_t1<<<4096, 512, 0, stream>>>(Ll, Bx, Llb, Pt1);
    reduce_t1<<<512, 256, 0, stream>>>(Pt1, T1l, B1);
    gemm_stage<1><<<512, 512, 0, stream>>>(Llb, B1, x, T2l, B2);
    // S3l (Llb L3-warm) overlapped with chain-u convert (HBM stream)
    fused_conv_s3<<<4608, 512, 0, stream>>>(Lu, Bx, Lub, Pt1,
                                            Llb, B2, T1l, T3l);
    // chain u (Lub L3-warm)
    reduce_t1<<<512, 256, 0, stream>>>(Pt1, T1u, B1);
    gemm_stage<1><<<512, 512, 0, stream>>>(Lub, B1, x, T2u, B2);
    gemm_stage<0><<<512, 512, 0, stream>>>(Lub, B2, T1u, T3u, nullptr);
  } else {
    gemm_f32_stage<0><<<512,512,0,stream>>>(Ll, (const short8v*)Bx, nullptr, T1l, B1);
    gemm_f32_stage<1><<<512,512,0,stream>>>(Ll, (const short8v*)B1, x,      T2l, B2);
    gemm_f32_stage<1><<<512,512,0,stream>>>(Ll, (const short8v*)B2, T1l,    T3l, B1);
    gemm_f32_stage<0><<<512,512,0,stream>>>(Lu, (const short8v*)Bx, nullptr, T1u, B1);
    gemm_f32_stage<1><<<512,512,0,stream>>>(Lu, (const short8v*)B1, x,      T2u, B2);
    gemm_f32_stage<1><<<512,512,0,stream>>>(Lu, (const short8v*)B2, T1u,    T3u, B1);
  }

  combine<<<1024, 256, 0, stream>>>(x, T1l, T2l, T3l, T1u, T2u, T3u, W, y);
}

// Round 11
// 253.206 us; speedup vs baseline: 1.0577x; 1.0577x over previous
//
#include <hip/hip_runtime.h>
#include <hip/hip_bf16.h>
#include <stdint.h>

#define Mdim 8192
#define KSTEPS 256        // 8192 / 32

typedef __attribute__((ext_vector_type(8))) short short8v;  // 8 bf16
typedef __attribute__((ext_vector_type(4))) float f32x4;
typedef __attribute__((ext_vector_type(2))) float f32x2;

// f32 -> bf16 RNE via standard cast (compiler emits v_cvt_pk_bf16_f32)
static __device__ __forceinline__ short bf16c(float f) {
  __hip_bfloat16 h = __float2bfloat16(f);
  union { __hip_bfloat16 h; short s; } c; c.h = h;
  return c.s;
}

// Repack x (f32 [8192][32]) into MFMA B-fragment layout:
// Bp[((ks*2 + h)*64 + lane)*8 + j] = bf16( B[ks*32 + (lane>>4)*8 + j][h*16 + (lane&15)] )
__global__ __launch_bounds__(256)
void repack_x(const float* __restrict__ x, short* __restrict__ Bp)
{
  int t = blockIdx.x * 256 + threadIdx.x;       // 32768 threads total
  int l = t & 63, h = (t >> 6) & 1, ks = t >> 7;
  int col = h * 16 + (l & 15);
  int kbase = ks * 32 + ((l >> 4) << 3);
  short8v v;
#pragma unroll
  for (int j = 0; j < 8; ++j) v[j] = bf16c(x[(size_t)(kbase + j) * 32 + col]);
  reinterpret_cast<short8v*>(Bp)[t] = v;
}

// Convert f32 L -> bf16 FRAGMENT-LINEAR layout AND accumulate this slab's
// partial of T1 = L @ x via MFMA (A-fragments are already in LDS; B = Bx).
// Block = (tile, slab): 16 rows x 1024 cols. 256 thr = 4 waves.
// Partial out: Pt1[(tile*8+slab)][512] f32 (16x32 tile, flat row*32+col).
// (round-9 proven version, 256 threads)
__global__ __launch_bounds__(256)
void convert_t1(const float* __restrict__ src, const short* __restrict__ Bx,
                short* __restrict__ dst, float* __restrict__ Pt1)
{
  __shared__ __align__(16) char sh[16 * 1032 * 2];   // 33 KB: Lb, then reused as Clf
  short (*Lb)[1032] = reinterpret_cast<short (*)[1032]>(sh);

  const int tile = blockIdx.x >> 3;       // 0..511 (16-row tile)
  const int slab = blockIdx.x & 7;        // 32 k-steps = 1024 columns
  const int t = threadIdx.x;
  const int lane = t & 63;
  const int wid  = t >> 6;

  // phase 1: 16 rows x 1024 f32 -> bf16 in LDS (coalesced, nontemporal)
  for (int i = 0; i < 16; ++i) {
    const f32x4* p = reinterpret_cast<const f32x4*>(
        src + ((size_t)tile * 16 + i) * Mdim + slab * 1024) + t;
    f32x4 a = __builtin_nontemporal_load(p);
    short* q = &Lb[i][t * 4];
    q[0] = bf16c(a[0]); q[1] = bf16c(a[1]); q[2] = bf16c(a[2]); q[3] = bf16c(a[3]);
  }
  __syncthreads();

  // phase 2: write fragment-linear records + MFMA partial T1.
  // iteration it: wave wid handles record ksl = it*4 + wid (all 64 lanes).
  const short8v* bx8 = reinterpret_cast<const short8v*>(Bx);
  f32x4 acc0 = {0.f, 0.f, 0.f, 0.f};
  f32x4 acc1 = {0.f, 0.f, 0.f, 0.f};
#pragma unroll
  for (int it = 0; it < 8; ++it) {
    const int ksl = it * 4 + wid;
    short8v av = *reinterpret_cast<const short8v*>(
        &Lb[lane & 15][ksl * 32 + ((lane >> 4) << 3)]);
    reinterpret_cast<short8v*>(dst)[(size_t)(tile * 256 + slab * 32 + ksl) * 64 + lane] = av;
    const int gks = slab * 32 + ksl;
    short8v b0 = bx8[(size_t)(gks << 1) * 64 + lane];
    short8v b1 = bx8[(size_t)((gks << 1) + 1) * 64 + lane];
    acc0 = __builtin_amdgcn_mfma_f32_16x16x32_bf16(av, b0, acc0, 0, 0, 0);
    acc1 = __builtin_amdgcn_mfma_f32_16x16x32_bf16(av, b1, acc1, 0, 0, 0);
  }

  // cross-wave reduce of the 4 partials (reuse LDS after barrier)
  __syncthreads();
  float* Clf = reinterpret_cast<float*>(sh);   // [4][16][32] = 8 KB
  {
    // C/D layout: col = lane&15, row = (lane>>4)*4 + reg  (m89-verified)
    const int crow = (lane >> 4) << 2;
    const int ccol = lane & 15;
#pragma unroll
    for (int q = 0; q < 4; ++q) {
      Clf[((wid * 16) + crow + q) * 32 + ccol] = acc0[q];
      Clf[((wid * 16) + crow + q) * 32 + 16 + ccol] = acc1[q];
    }
  }
  __syncthreads();
  {
    const int e = t * 2;
    const int row = e >> 5, col = e & 31;
    float v0 = Clf[row * 32 + col] + Clf[(16 + row) * 32 + col]
             + Clf[(32 + row) * 32 + col] + Clf[(48 + row) * 32 + col];
    float v1 = Clf[row * 32 + col + 1] + Clf[(16 + row) * 32 + col + 1]
             + Clf[(32 + row) * 32 + col + 1] + Clf[(48 + row) * 32 + col + 1];
    f32x2 o; o[0] = v0; o[1] = v1;
    *reinterpret_cast<f32x2*>(Pt1 + (size_t)(tile * 8 + slab) * 512 + e) = o;
  }
}

// Sum the 8 slab-partials -> T1 (f32) + T1 B-fragments.
__global__ __launch_bounds__(256)
void reduce_t1(const float* __restrict__ Pt1, float* __restrict__ Tout,
               short* __restrict__ BpOut)
{
  __shared__ float Cred[16][32];
  const int tile = blockIdx.x;
  const int t = threadIdx.x;
  const int e = t * 2;
  float s0 = 0.f, s1 = 0.f;
#pragma unroll
  for (int s = 0; s < 8; ++s) {
    f32x2 v = *reinterpret_cast<const f32x2*>(Pt1 + (size_t)(tile * 8 + s) * 512 + e);
    s0 += v[0]; s1 += v[1];
  }
  f32x2 o; o[0] = s0; o[1] = s1;
  *reinterpret_cast<f32x2*>(Tout + (size_t)tile * 512 + e) = o;
  Cred[e >> 5][e & 31] = s0;
  Cred[e >> 5][(e & 31) + 1] = s1;
  __syncthreads();
  if (t < 64) {
    const int r0 = tile << 4;
    const int ksOut = r0 >> 5;
    const int sub = (r0 >> 4) & 1;
    const int h = t >> 5;
    const int lp = (t & 31) + sub * 32;
    const int col = h * 16 + (lp & 15);
    const int lrbase = (lp & 16) ? 8 : 0;
    short8v v;
#pragma unroll
    for (int j = 0; j < 8; ++j) v[j] = bf16c(Cred[lrbase + j][col]);
    reinterpret_cast<short8v*>(BpOut)[(ksOut << 1 | h) * 64 + lp] = v;
  }
}

// Chebyshev GEMM stage, single chain: Tout = 2*(A @ B) - Tprev.
// A: bf16 FRAGMENT-LINEAR; B: fragment-packed bf16. 512 blocks x 512 thr
// (8 waves, K-split 8 x 1024). Round-9 proven structure.
// WRITEB=0 skips the B-fragment epilogue when no later stage consumes it.
template<int WRITEB>
__global__ __launch_bounds__(512)
void gemm_stage(const short* __restrict__ As, const short* __restrict__ Bps,
                const float* __restrict__ Tprev, float* __restrict__ Tout,
                short* __restrict__ BpOut)
{
  const int bTile = blockIdx.x;
  const int lane = threadIdx.x & 63;
  const int wid  = threadIdx.x >> 6;        // wave 0..7 -> k-chunk of 32 steps
  const int r0 = bTile << 4;
  const int ksbase = wid * 32;

  const short8v* aF = reinterpret_cast<const short8v*>(As)
                      + ((size_t)bTile * 256 + ksbase) * 64 + lane;
  const short8v* bF = reinterpret_cast<const short8v*>(Bps)
                      + (size_t)ksbase * 128 + lane;

  f32x4 acc0 = {0.f, 0.f, 0.f, 0.f};        // cols 0..15
  f32x4 acc1 = {0.f, 0.f, 0.f, 0.f};        // cols 16..31

#pragma unroll 8
  for (int ks = 0; ks < 32; ++ks) {
    short8v av = aF[ks * 64];
    short8v b0 = bF[ks * 128];
    short8v b1 = bF[ks * 128 + 64];
    acc0 = __builtin_amdgcn_mfma_f32_16x16x32_bf16(av, b0, acc0, 0, 0, 0);
    acc1 = __builtin_amdgcn_mfma_f32_16x16x32_bf16(av, b1, acc1, 0, 0, 0);
  }

  __shared__ float Cl[8][16][32];   // 16 KB partials
  __shared__ float Cred[16][32];    // 2 KB reduced tile
  {
    const int crow = (lane >> 4) << 2;
    const int ccol = lane & 15;
#pragma unroll
    for (int q = 0; q < 4; ++q) {
      Cl[wid][crow + q][ccol] = acc0[q];
      Cl[wid][crow + q][16 + ccol] = acc1[q];
    }
  }
  __syncthreads();
  {
    const int t = threadIdx.x;
    const int row = t >> 5, col = t & 31;
    float v = Cl[0][row][col] + Cl[1][row][col] + Cl[2][row][col] + Cl[3][row][col]
            + Cl[4][row][col] + Cl[5][row][col] + Cl[6][row][col] + Cl[7][row][col];
    v = 2.f * v - Tprev[(size_t)r0 * 32 + t];
    Tout[(size_t)r0 * 32 + t] = v;
    if constexpr (WRITEB) Cred[row][col] = v;
  }
  if constexpr (WRITEB) {
    __syncthreads();
    if (threadIdx.x < 64) {
      const int t = threadIdx.x;
      const int ksOut = r0 >> 5;
      const int sub = (r0 >> 4) & 1;
      const int h = t >> 5;
      const int lp = (t & 31) + sub * 32;
      const int col = h * 16 + (lp & 15);
      const int lrbase = (lp & 16) ? 8 : 0;
      short8v v;
#pragma unroll
      for (int j = 0; j < 8; ++j) v[j] = bf16c(Cred[lrbase + j][col]);
      reinterpret_cast<short8v*>(BpOut)[(ksOut << 1 | h) * 64 + lp] = v;
    }
  }
}

// Fallback f32-A stage (only if workspace lacks room for the bf16 copy).
template<int HASPREV>
__global__ __launch_bounds__(512)
void gemm_f32_stage(const float* __restrict__ Af, const short8v* __restrict__ Bp,
                    const float* __restrict__ Tprev, float* __restrict__ Tout,
                    short* __restrict__ BpOut)
{
  const int lane = threadIdx.x & 63;
  const int wid  = threadIdx.x >> 6;
  const int r0 = blockIdx.x << 4;
  const int arow = r0 + (lane & 15);
  const int koff = (lane >> 4) << 3;
  const int ksbase = wid * 32;

  f32x4 acc0 = {0.f, 0.f, 0.f, 0.f};
  f32x4 acc1 = {0.f, 0.f, 0.f, 0.f};

  const float* ap = Af + (size_t)arow * Mdim + ksbase * 32 + koff;
#pragma unroll 8
  for (int ks = 0; ks < 32; ++ks) {
    const int g = ksbase + ks;
    f32x4 a0 = *reinterpret_cast<const f32x4*>(ap);
    f32x4 a1 = *reinterpret_cast<const f32x4*>(ap + 4);
    short8v av;
#pragma unroll
    for (int j = 0; j < 4; ++j) av[j] = bf16c(a0[j]);
#pragma unroll
    for (int j = 0; j < 4; ++j) av[4 + j] = bf16c(a1[j]);
    short8v b0 = Bp[(g << 1) * 64 + lane];
    short8v b1 = Bp[((g << 1) + 1) * 64 + lane];
    acc0 = __builtin_amdgcn_mfma_f32_16x16x32_bf16(av, b0, acc0, 0, 0, 0);
    acc1 = __builtin_amdgcn_mfma_f32_16x16x32_bf16(av, b1, acc1, 0, 0, 0);
    ap += 32;
  }

  __shared__ float Cl[8][16][32];
  __shared__ float Cred[16][32];
  {
    const int crow = (lane >> 4) << 2;
    const int ccol = lane & 15;
#pragma unroll
    for (int q = 0; q < 4; ++q) {
      Cl[wid][crow + q][ccol] = acc0[q];
      Cl[wid][crow + q][16 + ccol] = acc1[q];
    }
  }
  __syncthreads();
  {
    const int t = threadIdx.x;
    const int row = t >> 5, col = t & 31;
    float v = Cl[0][row][col] + Cl[1][row][col] + Cl[2][row][col] + Cl[3][row][col]
            + Cl[4][row][col] + Cl[5][row][col] + Cl[6][row][col] + Cl[7][row][col];
    if constexpr (HASPREV) {
      v = 2.f * v - Tprev[(size_t)r0 * 32 + t];
    }
    Tout[(size_t)r0 * 32 + t] = v;
    Cred[row][col] = v;
  }
  __syncthreads();
  if (threadIdx.x < 64) {
    const int t = threadIdx.x;
    const int ksOut = r0 >> 5;
    const int sub = (r0 >> 4) & 1;
    const int h = t >> 5;
    const int lp = (t & 31) + sub * 32;
    const int col = h * 16 + (lp & 15);
    const int lrbase = (lp & 16) ? 8 : 0;
    short8v v;
#pragma unroll
    for (int j = 0; j < 8; ++j) v[j] = bf16c(Cred[lrbase + j][col]);
    reinterpret_cast<short8v*>(BpOut)[(ksOut << 1 | h) * 64 + lp] = v;
  }
}

// y[n][o] = sum_k sum_i Xk[n][i] * W[i][o][k],  W: [32][32][7] f32
__global__ __launch_bounds__(256)
void combine(const float* __restrict__ x,
             const float* __restrict__ T1l, const float* __restrict__ T2l,
             const float* __restrict__ T3l, const float* __restrict__ T1u,
             const float* __restrict__ T2u, const float* __restrict__ T3u,
             const float* __restrict__ W, float* __restrict__ y)
{
  __shared__ float Wl[7168];
  for (int i = threadIdx.x; i < 7168; i += 256) Wl[i] = W[i];
  __syncthreads();
  int t = blockIdx.x * 256 + threadIdx.x;
  int n = t >> 5, o = t & 31;
  const float* Xs[7] = {x, T1l, T2l, T3l, T1u, T2u, T3u};
  float sum = 0.f;
#pragma unroll
  for (int k = 0; k < 7; ++k) {
    const f32x4* Xr = reinterpret_cast<const f32x4*>(Xs[k] + (size_t)n * 32);
#pragma unroll
    for (int i4 = 0; i4 < 8; ++i4) {
      f32x4 xv = Xr[i4];
#pragma unroll
      for (int j = 0; j < 4; ++j)
        sum += xv[j] * Wl[(i4 * 4 + j) * 224 + o * 7 + k];
    }
  }
  y[t] = sum;
}

extern "C" void kernel_launch(void* const* d_in, const int* in_sizes, int n_in,
                              void* d_out, int out_size, void* d_ws, size_t ws_size,
                              hipStream_t stream)
{
  const float* x  = (const float*)d_in[0];
  const float* Ll = (const float*)d_in[1];
  const float* Lu = (const float*)d_in[2];
  const float* W  = (const float*)d_in[3];
  float* y = (float*)d_out;

  char* ws = (char*)d_ws;
  size_t off = 0;
  auto alloc = [&](size_t bytes) -> void* {
    void* p = ws + off; off += (bytes + 255) & ~(size_t)255; return p;
  };
  short* Bx = (short*)alloc(512 * 1024);
  short* B1 = (short*)alloc(512 * 1024);
  short* B2 = (short*)alloc(512 * 1024);
  float* T1l = (float*)alloc(1u << 20);
  float* T2l = (float*)alloc(1u << 20);
  float* T3l = (float*)alloc(1u << 20);
  float* T1u = (float*)alloc(1u << 20);
  float* T2u = (float*)alloc(1u << 20);
  float* T3u = (float*)alloc(1u << 20);
  float* Pt1 = (float*)alloc((size_t)512 * 8 * 512 * 4);   // 8 MB partials

  const size_t lbytes = (size_t)Mdim * Mdim * sizeof(short);
  bool useBF = (ws_size >= off + lbytes);
  short* Lab = nullptr;                     // ONE shared bf16 A buffer (both chains)
  if (useBF) Lab = (short*)alloc(lbytes);

  repack_x<<<128, 256, 0, stream>>>(x, Bx);

  if (useBF) {
    // ---- chain l (Lab stays L3-resident through its 3 consumers) ----
    convert_t1<<<4096, 256, 0, stream>>>(Ll, Bx, Lab, Pt1);
    reduce_t1<<<512, 256, 0, stream>>>(Pt1, T1l, B1);
    gemm_stage<1><<<512, 512, 0, stream>>>(Lab, B1, x,   T2l, B2);
    gemm_stage<0><<<512, 512, 0, stream>>>(Lab, B2, T1l, T3l, nullptr);
    // ---- chain u (reuse Lab: in-cache overwrite, no extra writeback) ----
    convert_t1<<<4096, 256, 0, stream>>>(Lu, Bx, Lab, Pt1);
    reduce_t1<<<512, 256, 0, stream>>>(Pt1, T1u, B1);
    gemm_stage<1><<<512, 512, 0, stream>>>(Lab, B1, x,   T2u, B2);
    gemm_stage<0><<<512, 512, 0, stream>>>(Lab, B2, T1u, T3u, nullptr);
  } else {
    gemm_f32_stage<0><<<512,512,0,stream>>>(Ll, (const short8v*)Bx, nullptr, T1l, B1);
    gemm_f32_stage<1><<<512,512,0,stream>>>(Ll, (const short8v*)B1, x,      T2l, B2);
    gemm_f32_stage<1><<<512,512,0,stream>>>(Ll, (const short8v*)B2, T1l,    T3l, B1);
    gemm_f32_stage<0><<<512,512,0,stream>>>(Lu, (const short8v*)Bx, nullptr, T1u, B1);
    gemm_f32_stage<1><<<512,512,0,stream>>>(Lu, (const short8v*)B1, x,      T2u, B2);
    gemm_f32_stage<1><<<512,512,0,stream>>>(Lu, (const short8v*)B2, T1u,    T3u, B1);
  }

  combine<<<1024, 256, 0, stream>>>(x, T1l, T2l, T3l, T1u, T2u, T3u, W, y);
}